// Round 1
// baseline (934.351 us; speedup 1.0000x reference)
//
#include <hip/hip_runtime.h>

// ValueNetwork: B=8192, N=96 (+1 self row), INPUT_DIM=64, SELF_DIM=16, HUMAN_DIM=48
// One block per batch element. fp32 throughout (threshold 9.4e-4 forbids naive bf16).
// Attention processed in 3 phases of 32 rows; only p[l] = sum_n A[0][n]*h1[n][l] is
// carried forward, so full A / AX / h1 are never materialized. LDS = 63.2 KB.

#define NP  100   // padded row count (97 valid, 3 zero pad)
#define STW 36    // S^T row stride (32 cols used + 4 pad, mult of 4 for b128)

__global__ __launch_bounds__(256, 2)
void vnet_kernel(const float* __restrict__ state,
                 const float* __restrict__ t_w1, const float* __restrict__ t_b1,
                 const float* __restrict__ t_w2, const float* __restrict__ t_b2,
                 const float* __restrict__ w_a,  const float* __restrict__ w1,
                 const float* __restrict__ w2,   const float* __restrict__ v_w1,
                 const float* __restrict__ v_b1, const float* __restrict__ v_w2,
                 const float* __restrict__ v_b2, float* __restrict__ out)
{
    // Xt[k][n] = X[n][k]  (X row 0 = new_self, rows 1..96 = human, 97..99 = 0)
    __shared__ __align__(16) float Xt[48][NP];      // 19200 B
    __shared__ __align__(16) float St[NP][STW];     // 14400 B  S^T then A^T; reused as h1blk[32][64]
    __shared__ __align__(16) float waL[48][48];     //  9216 B
    __shared__ __align__(16) float w1L[48][64];     // 12288 B
    __shared__ __align__(16) float Wb[48][32];      //  6144 B  Xw_blk^T then AX_blk^T
    __shared__ __align__(16) float a0c[NP];         //   400 B  A row 0
    __shared__ float ssb[16], hhb[52], xw0b[48], ax0b[48], s0b[NP], pbuf[64], featb[64];

    const int tid = threadIdx.x;
    const int b   = blockIdx.x;
    const float* sb = state + (size_t)b * (96 * 64);

    // ---- stage weights + build Xt ----
    for (int i = tid; i < 48 * 48; i += 256) waL[i / 48][i % 48] = w_a[i];
    for (int i = tid; i < 48 * 64; i += 256) w1L[i / 64][i % 64] = w1[i];
    if (tid < 16) ssb[tid] = sb[tid];
    for (int i = tid; i < 96 * 48; i += 256) {
        int r = i / 48, k = i - 48 * r;
        Xt[k][1 + r] = sb[r * 64 + 16 + k];
    }
    if (tid < 48 * 3) { int k = tid / 3, m = 97 + tid % 3; Xt[k][m] = 0.f; }
    if (tid < NP) a0c[tid] = 0.f;
    __syncthreads();

    // ---- self MLP: h = relu(self@t_w1+b1); new_self = relu(h@t_w2+b2) ----
    if (tid < 50) {
        float a = t_b1[tid];
        #pragma unroll
        for (int i = 0; i < 16; ++i) a = fmaf(ssb[i], t_w1[i * 50 + tid], a);
        hhb[tid] = fmaxf(a, 0.f);
    }
    __syncthreads();
    if (tid < 48) {
        float a = t_b2[tid];
        for (int i = 0; i < 50; ++i) a = fmaf(hhb[i], t_w2[i * 48 + tid], a);
        Xt[tid][0] = fmaxf(a, 0.f);
    }
    __syncthreads();

    // ---- row 0 special path ----
    if (tid < 48) {            // xw0 = X[0] @ w_a
        float a = 0.f;
        for (int k = 0; k < 48; ++k) a = fmaf(Xt[k][0], waL[k][tid], a);
        xw0b[tid] = a;
    }
    __syncthreads();
    if (tid < NP) {            // s0[m] = xw0 . X[m]
        float a = 0.f;
        for (int c = 0; c < 48; ++c) a = fmaf(xw0b[c], Xt[c][tid], a);
        s0b[tid] = a;
    }
    __syncthreads();
    if (tid < 64) {            // softmax row 0 -> a0c
        float x0 = (tid < 97)      ? s0b[tid]      : -1e30f;
        float x1 = (tid + 64 < 97) ? s0b[tid + 64] : -1e30f;
        float mx = fmaxf(x0, x1);
        #pragma unroll
        for (int d = 32; d >= 1; d >>= 1) mx = fmaxf(mx, __shfl_xor(mx, d));
        float e0 = (tid < 97)      ? __expf(x0 - mx) : 0.f;
        float e1 = (tid + 64 < 97) ? __expf(x1 - mx) : 0.f;
        float s = e0 + e1;
        #pragma unroll
        for (int d = 32; d >= 1; d >>= 1) s += __shfl_xor(s, d);
        float inv = 1.f / s;
        if (tid < 97)      a0c[tid]      = e0 * inv;
        if (tid + 64 < 97) a0c[tid + 64] = e1 * inv;
    }
    __syncthreads();
    if (tid < 48) {            // ax0[j] = sum_m a0[m] X[m][j]
        float a = 0.f;
        for (int m = 0; m < 97; ++m) a = fmaf(a0c[m], Xt[tid][m], a);
        ax0b[tid] = a;
    }
    __syncthreads();
    if (tid < 64) {            // h1 row 0, init p
        float a = 0.f;
        #pragma unroll 8
        for (int j = 0; j < 48; ++j) a = fmaf(ax0b[j], w1L[j][tid], a);
        pbuf[tid] = a0c[0] * fmaxf(a, 0.f);
    }
    __syncthreads();

    float* h1blk = &St[0][0];  // alias: [32][64] (A dead by the time it's written)

    // ---- 3 phases of 32 attention rows (global rows base..base+31) ----
    for (int p = 0; p < 3; ++p) {
        const int base = 1 + 32 * p;

        // (a) Xw_blk[ln][c] -> Wb[c][ln]   (192 tiles of 2n x 4c)
        if (tid < 192) {
            int nh = tid / 12, cq = tid % 12;
            int n0 = 2 * nh, c0 = 4 * cq;
            float a00=0,a01=0,a02=0,a03=0,a10=0,a11=0,a12=0,a13=0;
            #pragma unroll 4
            for (int k = 0; k < 48; ++k) {
                float x0 = Xt[k][base + n0], x1 = Xt[k][base + n0 + 1];
                float4 bv = *(const float4*)&waL[k][c0];
                a00 = fmaf(x0, bv.x, a00); a01 = fmaf(x0, bv.y, a01);
                a02 = fmaf(x0, bv.z, a02); a03 = fmaf(x0, bv.w, a03);
                a10 = fmaf(x1, bv.x, a10); a11 = fmaf(x1, bv.y, a11);
                a12 = fmaf(x1, bv.z, a12); a13 = fmaf(x1, bv.w, a13);
            }
            *(float2*)&Wb[c0 + 0][n0] = make_float2(a00, a10);
            *(float2*)&Wb[c0 + 1][n0] = make_float2(a01, a11);
            *(float2*)&Wb[c0 + 2][n0] = make_float2(a02, a12);
            *(float2*)&Wb[c0 + 3][n0] = make_float2(a03, a13);
        }
        __syncthreads();

        // (b) S[base+ln][m] -> St[m][ln]   (200 tiles of 4n x 4m)
        if (tid < 200) {
            int nq = tid / 25, mq = tid % 25;
            int n0 = 4 * nq, m0 = 4 * mq;
            float c00=0,c01=0,c02=0,c03=0,c10=0,c11=0,c12=0,c13=0;
            float c20=0,c21=0,c22=0,c23=0,c30=0,c31=0,c32=0,c33=0;
            #pragma unroll 4
            for (int c = 0; c < 48; ++c) {
                float4 av = *(const float4*)&Wb[c][n0];
                float4 bv = *(const float4*)&Xt[c][m0];
                c00 = fmaf(av.x, bv.x, c00); c01 = fmaf(av.x, bv.y, c01);
                c02 = fmaf(av.x, bv.z, c02); c03 = fmaf(av.x, bv.w, c03);
                c10 = fmaf(av.y, bv.x, c10); c11 = fmaf(av.y, bv.y, c11);
                c12 = fmaf(av.y, bv.z, c12); c13 = fmaf(av.y, bv.w, c13);
                c20 = fmaf(av.z, bv.x, c20); c21 = fmaf(av.z, bv.y, c21);
                c22 = fmaf(av.z, bv.z, c22); c23 = fmaf(av.z, bv.w, c23);
                c30 = fmaf(av.w, bv.x, c30); c31 = fmaf(av.w, bv.y, c31);
                c32 = fmaf(av.w, bv.z, c32); c33 = fmaf(av.w, bv.w, c33);
            }
            *(float4*)&St[m0 + 0][n0] = make_float4(c00, c10, c20, c30);
            *(float4*)&St[m0 + 1][n0] = make_float4(c01, c11, c21, c31);
            *(float4*)&St[m0 + 2][n0] = make_float4(c02, c12, c22, c32);
            *(float4*)&St[m0 + 3][n0] = make_float4(c03, c13, c23, c33);
        }
        __syncthreads();

        // (c) softmax over m for the 32 rows (8 lanes per row)
        {
            int ln = tid >> 3, mg = tid & 7;
            float mx = -1e30f;
            for (int m = mg; m < 97; m += 8) mx = fmaxf(mx, St[m][ln]);
            mx = fmaxf(mx, __shfl_xor(mx, 1));
            mx = fmaxf(mx, __shfl_xor(mx, 2));
            mx = fmaxf(mx, __shfl_xor(mx, 4));
            float s = 0.f;
            for (int m = mg; m < 97; m += 8) s += __expf(St[m][ln] - mx);
            s += __shfl_xor(s, 1); s += __shfl_xor(s, 2); s += __shfl_xor(s, 4);
            float inv = 1.f / s;
            for (int m = mg; m < 97; m += 8) St[m][ln] = __expf(St[m][ln] - mx) * inv;
            if (mg < 3) St[97 + mg][ln] = 0.f;
        }
        __syncthreads();

        // (d) AX[base+ln][j] -> Wb[j][ln]   (192 tiles of 2j x 4n)
        if (tid < 192) {
            int jh = tid >> 3, nq = tid & 7;
            int j0 = 2 * jh, n0 = 4 * nq;
            float c00=0,c01=0,c02=0,c03=0,c10=0,c11=0,c12=0,c13=0;
            #pragma unroll 4
            for (int m = 0; m < NP; ++m) {
                float x0 = Xt[j0][m], x1 = Xt[j0 + 1][m];
                float4 bv = *(const float4*)&St[m][n0];
                c00 = fmaf(x0, bv.x, c00); c01 = fmaf(x0, bv.y, c01);
                c02 = fmaf(x0, bv.z, c02); c03 = fmaf(x0, bv.w, c03);
                c10 = fmaf(x1, bv.x, c10); c11 = fmaf(x1, bv.y, c11);
                c12 = fmaf(x1, bv.z, c12); c13 = fmaf(x1, bv.w, c13);
            }
            *(float4*)&Wb[j0][n0]     = make_float4(c00, c01, c02, c03);
            *(float4*)&Wb[j0 + 1][n0] = make_float4(c10, c11, c12, c13);
        }
        __syncthreads();

        // (e) h1[base+c][l] = relu(sum_j AXbt[j][c] * w1[j][l]) -> h1blk[c][l]
        {
            int nh = tid >> 4, lq = tid & 15;
            int c0 = 2 * nh, l0 = 4 * lq;
            float e00=0,e01=0,e02=0,e03=0,e10=0,e11=0,e12=0,e13=0;
            #pragma unroll 4
            for (int j = 0; j < 48; ++j) {
                float x0 = Wb[j][c0], x1 = Wb[j][c0 + 1];
                float4 bv = *(const float4*)&w1L[j][l0];
                e00 = fmaf(x0, bv.x, e00); e01 = fmaf(x0, bv.y, e01);
                e02 = fmaf(x0, bv.z, e02); e03 = fmaf(x0, bv.w, e03);
                e10 = fmaf(x1, bv.x, e10); e11 = fmaf(x1, bv.y, e11);
                e12 = fmaf(x1, bv.z, e12); e13 = fmaf(x1, bv.w, e13);
            }
            *(float4*)&h1blk[(c0)     * 64 + l0] =
                make_float4(fmaxf(e00, 0.f), fmaxf(e01, 0.f), fmaxf(e02, 0.f), fmaxf(e03, 0.f));
            *(float4*)&h1blk[(c0 + 1) * 64 + l0] =
                make_float4(fmaxf(e10, 0.f), fmaxf(e11, 0.f), fmaxf(e12, 0.f), fmaxf(e13, 0.f));
        }
        __syncthreads();

        // (f) p[l] += sum_c a0[base+c] * h1blk[c][l]
        if (tid < 64) {
            float a = pbuf[tid];
            #pragma unroll 4
            for (int c = 0; c < 32; ++c) a = fmaf(a0c[base + c], h1blk[c * 64 + tid], a);
            pbuf[tid] = a;
        }
        __syncthreads();
    }

    // ---- head: feat = relu(p@w2); value = relu(feat@v_w1+v_b1)@v_w2 + v_b2 ----
    if (tid < 64) {
        float a = 0.f;
        #pragma unroll 8
        for (int l = 0; l < 64; ++l) a = fmaf(pbuf[l], w2[l * 64 + tid], a);
        featb[tid] = fmaxf(a, 0.f);
    }
    __syncthreads();
    if (tid < 64) {
        float a = v_b1[tid];
        #pragma unroll 8
        for (int c = 0; c < 64; ++c) a = fmaf(featb[c], v_w1[c * 64 + tid], a);
        float qd = fmaxf(a, 0.f) * v_w2[tid];
        #pragma unroll
        for (int d = 32; d >= 1; d >>= 1) qd += __shfl_xor(qd, d);
        if (tid == 0) out[b] = qd + v_b2[0];
    }
}

extern "C" void kernel_launch(void* const* d_in, const int* in_sizes, int n_in,
                              void* d_out, int out_size, void* d_ws, size_t ws_size,
                              hipStream_t stream) {
    (void)n_in; (void)d_ws; (void)ws_size; (void)out_size;
    const float* state = (const float*)d_in[0];
    const float* t_w1  = (const float*)d_in[1];
    const float* t_b1  = (const float*)d_in[2];
    const float* t_w2  = (const float*)d_in[3];
    const float* t_b2  = (const float*)d_in[4];
    const float* w_a   = (const float*)d_in[5];
    const float* w1    = (const float*)d_in[6];
    const float* w2    = (const float*)d_in[7];
    const float* v_w1  = (const float*)d_in[8];
    const float* v_b1  = (const float*)d_in[9];
    const float* v_w2  = (const float*)d_in[10];
    const float* v_b2  = (const float*)d_in[11];
    const int nb = in_sizes[0] / (96 * 64);   // 8192
    vnet_kernel<<<nb, 256, 0, stream>>>(state, t_w1, t_b1, t_w2, t_b2, w_a, w1,
                                        w2, v_w1, v_b1, v_w2, v_b2, (float*)d_out);
}

// Round 2
// 771.609 us; speedup vs baseline: 1.2109x; 1.2109x over previous
//
#include <hip/hip_runtime.h>

// ValueNetwork B=8192, rows=97 (1 self + 96 human), HUMAN_DIM=48.
// One block (256 thr, 4 waves) per batch. All four GEMMs (Xw, S, AX, h1) run on
// MFMA 16x16x32 bf16 with hi/lo split (3 MFMAs/product) for fp32-grade accuracy.
// 7 strips of 16 attention rows; only p[l] = sum_n A[0][n] h1[n][l] is carried.
// Operand arrays stored as bf16 hi/lo planes (split at write). A stored packed
// (hi16|lo16 per u32) for cheap softmax. K=48 via overlap chunk (16..47, quads
// 0-1 masked on A). K=112 via chunks {0,32,64,80-masked}. LDS ~59.4 KB.

#define XS 56    // X plane stride (ushort)
#define TS 120   // XT plane stride
#define AS 120   // A packed stride (u32)
#define WS 56    // Xw/AX plane stride

typedef short bf16x8 __attribute__((ext_vector_type(8)));
typedef float f32x4 __attribute__((ext_vector_type(4)));

__device__ __forceinline__ unsigned rtne_hi(float f) {
    unsigned u = __float_as_uint(f);
    return (u + 0x7fffu + ((u >> 16) & 1u)) & 0xffff0000u;
}
__device__ __forceinline__ void split2(float f, unsigned short* h, unsigned short* l) {
    unsigned hb = rtne_hi(f);
    float r = f - __uint_as_float(hb);
    *h = (unsigned short)(hb >> 16);
    *l = (unsigned short)(__float_as_uint(r) >> 16);
}
__device__ __forceinline__ unsigned packw(float f) {
    unsigned hb = rtne_hi(f);
    float r = f - __uint_as_float(hb);
    return hb | (__float_as_uint(r) >> 16);
}
__device__ __forceinline__ float unpackw(unsigned w) {
    return __uint_as_float(w & 0xffff0000u) + __uint_as_float(w << 16);
}
__device__ __forceinline__ bf16x8 ldf(const unsigned short* p) {
    return *(const bf16x8*)p;
}

__global__ void vnet_prep(const float* __restrict__ w_a, const float* __restrict__ w1,
                          unsigned short* __restrict__ ws) {
    // waT[c][k] = w_a[k][c] hi/lo planes; w1T[l][j] = w1[j][l] hi/lo planes.
    unsigned short* waT_h = ws;                 // 48*48
    unsigned short* waT_l = ws + 2304;
    unsigned short* w1T_h = ws + 4608;          // 64*48
    unsigned short* w1T_l = ws + 4608 + 3072;
    for (int i = threadIdx.x; i < 48 * 48; i += blockDim.x) {
        int c = i / 48, k = i % 48;
        unsigned short h, l; split2(w_a[k * 48 + c], &h, &l);
        waT_h[i] = h; waT_l[i] = l;
    }
    for (int i = threadIdx.x; i < 64 * 48; i += blockDim.x) {
        int lo = i / 48, j = i % 48;
        unsigned short h, l; split2(w1[j * 64 + lo], &h, &l);
        w1T_h[i] = h; w1T_l[i] = l;
    }
}

__global__ __launch_bounds__(256, 2)
void vnet_kernel(const float* __restrict__ state,
                 const float* __restrict__ t_w1, const float* __restrict__ t_b1,
                 const float* __restrict__ t_w2, const float* __restrict__ t_b2,
                 const float* __restrict__ w2,   const float* __restrict__ v_w1,
                 const float* __restrict__ v_b1, const float* __restrict__ v_w2,
                 const float* __restrict__ v_b2, const unsigned short* __restrict__ ws,
                 float* __restrict__ out)
{
    __shared__ __align__(16) unsigned short Xh[112 * XS], Xl[112 * XS];   // 12544B each
    __shared__ __align__(16) unsigned short XTh[48 * TS], XTl[48 * TS];   // 11520B each
    __shared__ __align__(16) unsigned APk[16 * AS];                       // 7680B
    __shared__ __align__(16) unsigned short Wh[16 * WS], Wl[16 * WS];     // 1792B each (Xw, then AX)
    __shared__ float a0c[112];
    __shared__ float pacc[64];
    __shared__ float nsb[48], ssb[16], hhb[52], featb[64];

    const unsigned short* waT_h = ws;
    const unsigned short* waT_l = ws + 2304;
    const unsigned short* w1T_h = ws + 4608;
    const unsigned short* w1T_l = ws + 4608 + 3072;

    const int tid  = threadIdx.x;
    const int w    = tid >> 6;
    const int lane = tid & 63;
    const int row  = lane & 15;
    const int quad = lane >> 4;
    const int b    = blockIdx.x;
    const float* sb = state + (size_t)b * (96 * 64);
    const bf16x8 ZF = {0, 0, 0, 0, 0, 0, 0, 0};

    // ---------- init: stage X (rows 1..96) + XT from global ----------
    if (tid < 16) ssb[tid] = sb[tid];
    for (int i = tid; i < 96 * 12; i += 256) {
        int r = i / 12, q = i % 12;
        float4 v = *(const float4*)(sb + r * 64 + 16 + 4 * q);
        int xr = 1 + r, cb = 4 * q;
        unsigned short h0, l0, h1v, l1, h2, l2, h3, l3;
        split2(v.x, &h0, &l0); split2(v.y, &h1v, &l1);
        split2(v.z, &h2, &l2); split2(v.w, &h3, &l3);
        *(unsigned*)&Xh[xr * XS + cb]     = (unsigned)h0 | ((unsigned)h1v << 16);
        *(unsigned*)&Xh[xr * XS + cb + 2] = (unsigned)h2 | ((unsigned)h3 << 16);
        *(unsigned*)&Xl[xr * XS + cb]     = (unsigned)l0 | ((unsigned)l1 << 16);
        *(unsigned*)&Xl[xr * XS + cb + 2] = (unsigned)l2 | ((unsigned)l3 << 16);
    }
    for (int i = tid; i < 48 * 96; i += 256) {
        int c = i % 48, rm = i / 48, m = 1 + rm;
        unsigned short h, l; split2(sb[rm * 64 + 16 + c], &h, &l);
        XTh[c * TS + m] = h; XTl[c * TS + m] = l;
    }
    for (int i = tid; i < 15 * 48; i += 256) {   // zero pad rows 97..111
        int r = 97 + i / 48, c = i % 48;
        Xh[r * XS + c] = 0; Xl[r * XS + c] = 0;
    }
    for (int i = tid; i < 48 * 23; i += 256) {   // zero XT cols 97..119
        int c = i / 23, m = 97 + i % 23;
        XTh[c * TS + m] = 0; XTl[c * TS + m] = 0;
    }
    if (tid < 112) a0c[tid] = 0.f;
    if (tid < 64) pacc[tid] = 0.f;
    __syncthreads();

    // ---------- self MLP -> new_self (X row 0, XT col 0) ----------
    if (tid < 50) {
        float a = t_b1[tid];
        #pragma unroll
        for (int i = 0; i < 16; ++i) a = fmaf(ssb[i], t_w1[i * 50 + tid], a);
        hhb[tid] = fmaxf(a, 0.f);
    }
    __syncthreads();
    if (tid < 48) {
        float a = t_b2[tid];
        for (int i = 0; i < 50; ++i) a = fmaf(hhb[i], t_w2[i * 48 + tid], a);
        nsb[tid] = fmaxf(a, 0.f);
    }
    __syncthreads();
    if (tid < 48) {
        unsigned short h, l; split2(nsb[tid], &h, &l);
        Xh[tid] = h; Xl[tid] = l;            // X row 0
        XTh[tid * TS] = h; XTl[tid * TS] = l; // XT col 0
    }
    __syncthreads();

    // ---------- 7 strips of 16 attention rows ----------
    for (int s = 0; s < 7; ++s) {
        const int n0g = s * 16;

        // step 1: Xw strip = X[n-strip] @ w_a  -> Wh/Wl planes [16][48]
        if (w < 3) {
            f32x4 acc = {0.f, 0.f, 0.f, 0.f};
            #pragma unroll
            for (int ch = 0; ch < 2; ++ch) {
                int kb = 16 * ch;
                bf16x8 ah = ldf(&Xh[(n0g + row) * XS + kb + quad * 8]);
                bf16x8 al = ldf(&Xl[(n0g + row) * XS + kb + quad * 8]);
                if (ch == 1 && quad < 2) { ah = ZF; al = ZF; }
                bf16x8 bh = ldf(waT_h + (16 * w + row) * 48 + kb + quad * 8);
                bf16x8 bl = ldf(waT_l + (16 * w + row) * 48 + kb + quad * 8);
                acc = __builtin_amdgcn_mfma_f32_16x16x32_bf16(ah, bh, acc, 0, 0, 0);
                acc = __builtin_amdgcn_mfma_f32_16x16x32_bf16(ah, bl, acc, 0, 0, 0);
                acc = __builtin_amdgcn_mfma_f32_16x16x32_bf16(al, bh, acc, 0, 0, 0);
            }
            #pragma unroll
            for (int r = 0; r < 4; ++r) {
                unsigned short h, l; split2(acc[r], &h, &l);
                Wh[(quad * 4 + r) * WS + 16 * w + row] = h;
                Wl[(quad * 4 + r) * WS + 16 * w + row] = l;
            }
        }
        __syncthreads();

        // step 2: S strip = Xw @ X^T -> APk packed
        {
            bf16x8 a0h = ldf(&Wh[row * WS + quad * 8]);
            bf16x8 a0l = ldf(&Wl[row * WS + quad * 8]);
            bf16x8 a1h = ldf(&Wh[row * WS + 16 + quad * 8]);
            bf16x8 a1l = ldf(&Wl[row * WS + 16 + quad * 8]);
            if (quad < 2) { a1h = ZF; a1l = ZF; }
            for (int t = w; t < 7; t += 4) {
                int m = 16 * t + row;
                f32x4 acc = {0.f, 0.f, 0.f, 0.f};
                bf16x8 bh = ldf(&Xh[m * XS + quad * 8]);
                bf16x8 bl = ldf(&Xl[m * XS + quad * 8]);
                acc = __builtin_amdgcn_mfma_f32_16x16x32_bf16(a0h, bh, acc, 0, 0, 0);
                acc = __builtin_amdgcn_mfma_f32_16x16x32_bf16(a0h, bl, acc, 0, 0, 0);
                acc = __builtin_amdgcn_mfma_f32_16x16x32_bf16(a0l, bh, acc, 0, 0, 0);
                bh = ldf(&Xh[m * XS + 16 + quad * 8]);
                bl = ldf(&Xl[m * XS + 16 + quad * 8]);
                acc = __builtin_amdgcn_mfma_f32_16x16x32_bf16(a1h, bh, acc, 0, 0, 0);
                acc = __builtin_amdgcn_mfma_f32_16x16x32_bf16(a1h, bl, acc, 0, 0, 0);
                acc = __builtin_amdgcn_mfma_f32_16x16x32_bf16(a1l, bh, acc, 0, 0, 0);
                #pragma unroll
                for (int r = 0; r < 4; ++r)
                    APk[(quad * 4 + r) * AS + 16 * t + row] = packw(acc[r]);
            }
        }
        __syncthreads();

        // step 3: softmax over m<97 for the 16 rows; write A packed
        {
            int rw = tid >> 4, mg = tid & 15;
            float mx = -1e30f;
            for (int m = mg; m < 97; m += 16)
                mx = fmaxf(mx, __uint_as_float(APk[rw * AS + m] & 0xffff0000u));
            mx = fmaxf(mx, __shfl_xor(mx, 1)); mx = fmaxf(mx, __shfl_xor(mx, 2));
            mx = fmaxf(mx, __shfl_xor(mx, 4)); mx = fmaxf(mx, __shfl_xor(mx, 8));
            float sum = 0.f;
            for (int m = mg; m < 97; m += 16) {
                float f = unpackw(APk[rw * AS + m]);
                float e = __expf(f - mx);
                sum += e;
                APk[rw * AS + m] = packw(e);
            }
            sum += __shfl_xor(sum, 1); sum += __shfl_xor(sum, 2);
            sum += __shfl_xor(sum, 4); sum += __shfl_xor(sum, 8);
            float inv = 1.f / sum;
            for (int m = mg; m < 97; m += 16) {
                float a = unpackw(APk[rw * AS + m]) * inv;
                APk[rw * AS + m] = packw(a);
                if (s == 0 && rw == 0) a0c[m] = a;
            }
            for (int m = 97 + mg; m < 120; m += 16) APk[rw * AS + m] = 0u;
        }
        __syncthreads();

        // step 4: AX strip = A @ X -> Wh/Wl planes [16][48] (Xw dead)
        if (w < 3) {
            f32x4 acc = {0.f, 0.f, 0.f, 0.f};
            #pragma unroll
            for (int c = 0; c < 4; ++c) {
                int mb = (c < 3) ? 32 * c : 80;
                const unsigned* ap = &APk[row * AS + mb + quad * 8];
                uint4 u0 = *(const uint4*)ap;
                uint4 u1 = *(const uint4*)(ap + 4);
                bf16x8 ah, al;
                ah[0] = (short)(u0.x >> 16); al[0] = (short)u0.x;
                ah[1] = (short)(u0.y >> 16); al[1] = (short)u0.y;
                ah[2] = (short)(u0.z >> 16); al[2] = (short)u0.z;
                ah[3] = (short)(u0.w >> 16); al[3] = (short)u0.w;
                ah[4] = (short)(u1.x >> 16); al[4] = (short)u1.x;
                ah[5] = (short)(u1.y >> 16); al[5] = (short)u1.y;
                ah[6] = (short)(u1.z >> 16); al[6] = (short)u1.z;
                ah[7] = (short)(u1.w >> 16); al[7] = (short)u1.w;
                if (c == 3 && quad < 2) { ah = ZF; al = ZF; }
                bf16x8 bh = ldf(&XTh[(16 * w + row) * TS + mb + quad * 8]);
                bf16x8 bl = ldf(&XTl[(16 * w + row) * TS + mb + quad * 8]);
                acc = __builtin_amdgcn_mfma_f32_16x16x32_bf16(ah, bh, acc, 0, 0, 0);
                acc = __builtin_amdgcn_mfma_f32_16x16x32_bf16(ah, bl, acc, 0, 0, 0);
                acc = __builtin_amdgcn_mfma_f32_16x16x32_bf16(al, bh, acc, 0, 0, 0);
            }
            __syncthreads();   // Wh still holds Xw for step-2 readers? no: step2 done; sync before overwrite below
            #pragma unroll
            for (int r = 0; r < 4; ++r) {
                unsigned short h, l; split2(acc[r], &h, &l);
                Wh[(quad * 4 + r) * WS + 16 * w + row] = h;
                Wl[(quad * 4 + r) * WS + 16 * w + row] = l;
            }
        } else {
            __syncthreads();
        }
        __syncthreads();

        // step 5: h1 strip = relu(AX @ w1); p += a0-weighted rows
        {
            f32x4 acc = {0.f, 0.f, 0.f, 0.f};
            #pragma unroll
            for (int ch = 0; ch < 2; ++ch) {
                int kb = 16 * ch;
                bf16x8 ah = ldf(&Wh[row * WS + kb + quad * 8]);
                bf16x8 al = ldf(&Wl[row * WS + kb + quad * 8]);
                if (ch == 1 && quad < 2) { ah = ZF; al = ZF; }
                bf16x8 bh = ldf(w1T_h + (16 * w + row) * 48 + kb + quad * 8);
                bf16x8 bl = ldf(w1T_l + (16 * w + row) * 48 + kb + quad * 8);
                acc = __builtin_amdgcn_mfma_f32_16x16x32_bf16(ah, bh, acc, 0, 0, 0);
                acc = __builtin_amdgcn_mfma_f32_16x16x32_bf16(ah, bl, acc, 0, 0, 0);
                acc = __builtin_amdgcn_mfma_f32_16x16x32_bf16(al, bh, acc, 0, 0, 0);
            }
            float part = 0.f;
            #pragma unroll
            for (int r = 0; r < 4; ++r)
                part += fmaxf(acc[r], 0.f) * a0c[n0g + quad * 4 + r];
            part += __shfl_xor(part, 16);
            part += __shfl_xor(part, 32);
            if (quad == 0) pacc[16 * w + row] += part;
        }
        __syncthreads();
    }

    // ---------- head ----------
    if (tid < 64) {
        float a = 0.f;
        #pragma unroll 8
        for (int l = 0; l < 64; ++l) a = fmaf(pacc[l], w2[l * 64 + tid], a);
        featb[tid] = fmaxf(a, 0.f);
    }
    __syncthreads();
    if (tid < 64) {
        float a = v_b1[tid];
        #pragma unroll 8
        for (int c = 0; c < 64; ++c) a = fmaf(featb[c], v_w1[c * 64 + tid], a);
        float qd = fmaxf(a, 0.f) * v_w2[tid];
        #pragma unroll
        for (int d = 32; d >= 1; d >>= 1) qd += __shfl_xor(qd, d);
        if (tid == 0) out[b] = qd + v_b2[0];
    }
}

extern "C" void kernel_launch(void* const* d_in, const int* in_sizes, int n_in,
                              void* d_out, int out_size, void* d_ws, size_t ws_size,
                              hipStream_t stream) {
    (void)n_in; (void)ws_size; (void)out_size;
    const float* state = (const float*)d_in[0];
    const float* t_w1  = (const float*)d_in[1];
    const float* t_b1  = (const float*)d_in[2];
    const float* t_w2  = (const float*)d_in[3];
    const float* t_b2  = (const float*)d_in[4];
    const float* w_a   = (const float*)d_in[5];
    const float* w1    = (const float*)d_in[6];
    const float* w2    = (const float*)d_in[7];
    const float* v_w1  = (const float*)d_in[8];
    const float* v_b1  = (const float*)d_in[9];
    const float* v_w2  = (const float*)d_in[10];
    const float* v_b2  = (const float*)d_in[11];
    unsigned short* ws = (unsigned short*)d_ws;
    const int nb = in_sizes[0] / (96 * 64);   // 8192

    vnet_prep<<<1, 256, 0, stream>>>(w_a, w1, ws);
    vnet_kernel<<<nb, 256, 0, stream>>>(state, t_w1, t_b1, t_w2, t_b2, w2,
                                        v_w1, v_b1, v_w2, v_b2, ws, (float*)d_out);
}

// Round 3
// 664.973 us; speedup vs baseline: 1.4051x; 1.1604x over previous
//
#include <hip/hip_runtime.h>

// ValueNetwork B=8192, rows=97 (1 self + 96 human), HUMAN_DIM=48.
// One block (256 thr) per batch. GEMMs on MFMA 16x16x32 bf16 hi/lo split
// (3 MFMAs/product). 7 strips of 16 rows; only p[l]=sum_n A[0][n]h1[n][l] kept.
// R3 changes vs R2: single split + LDS transpose for XT; 1-pass softmax
// (no max-sub, 1/sum folded into step-4 via invb); E stored as bf16 hi/lo
// planes (b128 A-frag loads, no unpack); LDS 53,952B -> 3 blocks/CU;
// strides chosen for <=2-way bank aliasing (free).

#define XS 48     // X plane row stride (ushort)
#define TS 120    // XT plane row stride (ushort)
#define ES 120    // E plane row stride (ushort)
#define WS 56     // W (Xw/AX) plane row stride (ushort)

typedef short bf16x8 __attribute__((ext_vector_type(8)));
typedef float f32x4 __attribute__((ext_vector_type(4)));

__device__ __forceinline__ unsigned rtne_hi(float f) {
    unsigned u = __float_as_uint(f);
    return (u + 0x7fffu + ((u >> 16) & 1u)) & 0xffff0000u;
}
__device__ __forceinline__ void split2(float f, unsigned short* h, unsigned short* l) {
    unsigned hb = rtne_hi(f);
    float r = f - __uint_as_float(hb);
    *h = (unsigned short)(hb >> 16);
    *l = (unsigned short)(__float_as_uint(r) >> 16);
}
__device__ __forceinline__ float bf2f(unsigned short u) {
    return __uint_as_float(((unsigned)u) << 16);
}
__device__ __forceinline__ bf16x8 ldf(const unsigned short* p) {
    return *(const bf16x8*)p;
}

__global__ void vnet_prep(const float* __restrict__ w_a, const float* __restrict__ w1,
                          unsigned short* __restrict__ ws) {
    // waT[c][k] = w_a[k][c] hi/lo planes; w1T[l][j] = w1[j][l] hi/lo planes.
    unsigned short* waT_h = ws;                 // 48*48
    unsigned short* waT_l = ws + 2304;
    unsigned short* w1T_h = ws + 4608;          // 64*48
    unsigned short* w1T_l = ws + 4608 + 3072;
    for (int i = threadIdx.x; i < 48 * 48; i += blockDim.x) {
        int c = i / 48, k = i % 48;
        unsigned short h, l; split2(w_a[k * 48 + c], &h, &l);
        waT_h[i] = h; waT_l[i] = l;
    }
    for (int i = threadIdx.x; i < 64 * 48; i += blockDim.x) {
        int lo = i / 48, j = i % 48;
        unsigned short h, l; split2(w1[j * 64 + lo], &h, &l);
        w1T_h[i] = h; w1T_l[i] = l;
    }
}

__global__ __launch_bounds__(256, 3)
void vnet_kernel(const float* __restrict__ state,
                 const float* __restrict__ t_w1, const float* __restrict__ t_b1,
                 const float* __restrict__ t_w2, const float* __restrict__ t_b2,
                 const float* __restrict__ w2,   const float* __restrict__ v_w1,
                 const float* __restrict__ v_b1, const float* __restrict__ v_w2,
                 const float* __restrict__ v_b2, const unsigned short* __restrict__ ws,
                 float* __restrict__ out)
{
    __shared__ __align__(16) unsigned short Xh[97 * XS], Xl[97 * XS];     // 9312B each
    __shared__ __align__(16) unsigned short XTh[48 * TS], XTl[48 * TS];   // 11520B each
    __shared__ __align__(16) unsigned short Eh[16 * ES], El[16 * ES];     // 3840B each
    __shared__ __align__(16) unsigned short Wh[16 * WS], Wl[16 * WS];     // 1792B each
    __shared__ float a0c[112];    // A row 0 (fp32); [97..111]=0
    __shared__ float invb[16];    // per-strip-row 1/sum
    __shared__ float pacc[64];    // also self-state temp
    __shared__ float featb[64];   // also new_self temp

    const unsigned short* waT_h = ws;
    const unsigned short* waT_l = ws + 2304;
    const unsigned short* w1T_h = ws + 4608;
    const unsigned short* w1T_l = ws + 4608 + 3072;

    const int tid  = threadIdx.x;
    const int w    = tid >> 6;
    const int lane = tid & 63;
    const int row  = lane & 15;
    const int quad = lane >> 4;
    const int b    = blockIdx.x;
    const float* sb = state + (size_t)b * (96 * 64);
    const bf16x8 ZF = {0, 0, 0, 0, 0, 0, 0, 0};

    // ---------- stage X rows 1..96 (single split) ----------
    if (tid < 16) pacc[tid] = sb[tid];           // self-state temp
    for (int i = tid; i < 96 * 12; i += 256) {
        int r = i / 12, q = i % 12;
        float4 v = *(const float4*)(sb + r * 64 + 16 + 4 * q);
        unsigned short h0, l0, h1v, l1, h2, l2, h3, l3;
        split2(v.x, &h0, &l0); split2(v.y, &h1v, &l1);
        split2(v.z, &h2, &l2); split2(v.w, &h3, &l3);
        int o = (1 + r) * XS + 4 * q;
        *(uint2*)&Xh[o] = make_uint2((unsigned)h0 | ((unsigned)h1v << 16),
                                     (unsigned)h2 | ((unsigned)h3 << 16));
        *(uint2*)&Xl[o] = make_uint2((unsigned)l0 | ((unsigned)l1 << 16),
                                     (unsigned)l2 | ((unsigned)l3 << 16));
    }
    __syncthreads();

    // ---------- self MLP -> X row 0 ----------
    if (tid < 50) {
        float a = t_b1[tid];
        #pragma unroll
        for (int i = 0; i < 16; ++i) a = fmaf(pacc[i], t_w1[i * 50 + tid], a);
        a0c[tid] = fmaxf(a, 0.f);                // hidden temp
    }
    __syncthreads();
    if (tid < 48) {
        float a = t_b2[tid];
        for (int i = 0; i < 50; ++i) a = fmaf(a0c[i], t_w2[i * 48 + tid], a);
        featb[tid] = fmaxf(a, 0.f);              // new_self temp
    }
    __syncthreads();
    if (tid < 48) {
        unsigned short h, l; split2(featb[tid], &h, &l);
        Xh[tid] = h; Xl[tid] = l;                // X row 0
    }
    if (tid >= 64 && tid < 79) a0c[33 + tid] = 0.f;      // a0c[97..111] = 0
    if (tid >= 128 && tid < 192) pacc[tid - 128] = 0.f;  // p accumulator = 0
    __syncthreads();

    // ---------- XT = X^T via LDS copy (values already split) ----------
    for (int i = tid; i < 97 * 48; i += 256) {
        int m = i / 48, c = i - 48 * m;
        XTh[c * TS + m] = Xh[m * XS + c];
        XTl[c * TS + m] = Xl[m * XS + c];
    }
    for (int i = tid; i < 48 * 15; i += 256) {   // zero XT cols 97..111
        int c = i / 15, m = 97 + i % 15;
        XTh[c * TS + m] = 0; XTl[c * TS + m] = 0;
    }
    __syncthreads();

    // ---------- 7 strips of 16 attention rows ----------
    for (int s = 0; s < 7; ++s) {
        const int n0g = s * 16;

        // step 1: Xw strip = X[strip] @ w_a -> Wh/Wl [16][48] (row-major)
        if (w < 3) {
            f32x4 acc = {0.f, 0.f, 0.f, 0.f};
            int n = n0g + row; int nc = n < 97 ? n : 96;   // strip 6 tail clamp
            #pragma unroll
            for (int ch = 0; ch < 2; ++ch) {
                int kb = 16 * ch;
                bf16x8 ah = ldf(&Xh[nc * XS + kb + quad * 8]);
                bf16x8 al = ldf(&Xl[nc * XS + kb + quad * 8]);
                if (ch == 1 && quad < 2) { ah = ZF; al = ZF; }
                bf16x8 bh = ldf(waT_h + (16 * w + row) * 48 + kb + quad * 8);
                bf16x8 bl = ldf(waT_l + (16 * w + row) * 48 + kb + quad * 8);
                acc = __builtin_amdgcn_mfma_f32_16x16x32_bf16(ah, bh, acc, 0, 0, 0);
                acc = __builtin_amdgcn_mfma_f32_16x16x32_bf16(ah, bl, acc, 0, 0, 0);
                acc = __builtin_amdgcn_mfma_f32_16x16x32_bf16(al, bh, acc, 0, 0, 0);
            }
            #pragma unroll
            for (int r = 0; r < 4; ++r) {
                unsigned short h, l; split2(acc[r], &h, &l);
                Wh[(quad * 4 + r) * WS + 16 * w + row] = h;
                Wl[(quad * 4 + r) * WS + 16 * w + row] = l;
            }
        }
        __syncthreads();

        // step 2: S strip = Xw @ X^T -> Eh/El planes (raw scores)
        {
            bf16x8 a0h = ldf(&Wh[row * WS + quad * 8]);
            bf16x8 a0l = ldf(&Wl[row * WS + quad * 8]);
            bf16x8 a1h = ldf(&Wh[row * WS + 16 + quad * 8]);
            bf16x8 a1l = ldf(&Wl[row * WS + 16 + quad * 8]);
            if (quad < 2) { a1h = ZF; a1l = ZF; }
            for (int t = w; t < 7; t += 4) {
                int m = 16 * t + row; int mc = m < 97 ? m : 96;  // t=6 tail clamp
                f32x4 acc = {0.f, 0.f, 0.f, 0.f};
                bf16x8 bh = ldf(&Xh[mc * XS + quad * 8]);
                bf16x8 bl = ldf(&Xl[mc * XS + quad * 8]);
                acc = __builtin_amdgcn_mfma_f32_16x16x32_bf16(a0h, bh, acc, 0, 0, 0);
                acc = __builtin_amdgcn_mfma_f32_16x16x32_bf16(a0h, bl, acc, 0, 0, 0);
                acc = __builtin_amdgcn_mfma_f32_16x16x32_bf16(a0l, bh, acc, 0, 0, 0);
                bh = ldf(&Xh[mc * XS + 16 + quad * 8]);
                bl = ldf(&Xl[mc * XS + 16 + quad * 8]);
                acc = __builtin_amdgcn_mfma_f32_16x16x32_bf16(a1h, bh, acc, 0, 0, 0);
                acc = __builtin_amdgcn_mfma_f32_16x16x32_bf16(a1h, bl, acc, 0, 0, 0);
                acc = __builtin_amdgcn_mfma_f32_16x16x32_bf16(a1l, bh, acc, 0, 0, 0);
                #pragma unroll
                for (int r = 0; r < 4; ++r) {
                    unsigned short h, l; split2(acc[r], &h, &l);
                    Eh[(quad * 4 + r) * ES + m] = h;
                    El[(quad * 4 + r) * ES + m] = l;
                }
            }
        }
        __syncthreads();

        // step 3: one-pass softmax numerator: E = exp(S) in place, invb = 1/sum
        // (|S| <= ~9 by norm bound, no max subtraction needed in fp32)
        {
            int rw = tid >> 4, mg = tid & 15;
            float sum = 0.f;
            for (int m = mg; m < 97; m += 16) {
                int o = rw * ES + m;
                float f = bf2f(Eh[o]) + bf2f(El[o]);
                float e = __expf(f);
                sum += e;
                unsigned short h, l; split2(e, &h, &l);
                Eh[o] = h; El[o] = l;
                if (s == 0 && rw == 0) a0c[m] = e;   // unnormalized; wave3 scales
            }
            sum += __shfl_xor(sum, 1); sum += __shfl_xor(sum, 2);
            sum += __shfl_xor(sum, 4); sum += __shfl_xor(sum, 8);
            if (mg == 0) invb[rw] = 1.f / sum;
            for (int m = 97 + mg; m < 112; m += 16) {  // zero pads (NaN guard)
                Eh[rw * ES + m] = 0; El[rw * ES + m] = 0;
            }
        }
        __syncthreads();

        // step 4: AX strip = invb * (E @ X) -> Wh/Wl [16][48] (Xw dead)
        if (w < 3) {
            f32x4 acc = {0.f, 0.f, 0.f, 0.f};
            #pragma unroll
            for (int c = 0; c < 4; ++c) {
                int mb = (c < 3) ? 32 * c : 80;
                bf16x8 ah = ldf(&Eh[row * ES + mb + quad * 8]);
                bf16x8 al = ldf(&El[row * ES + mb + quad * 8]);
                if (c == 3 && quad < 2) { ah = ZF; al = ZF; }  // avoid 80..95 double count
                bf16x8 bh = ldf(&XTh[(16 * w + row) * TS + mb + quad * 8]);
                bf16x8 bl = ldf(&XTl[(16 * w + row) * TS + mb + quad * 8]);
                acc = __builtin_amdgcn_mfma_f32_16x16x32_bf16(ah, bh, acc, 0, 0, 0);
                acc = __builtin_amdgcn_mfma_f32_16x16x32_bf16(ah, bl, acc, 0, 0, 0);
                acc = __builtin_amdgcn_mfma_f32_16x16x32_bf16(al, bh, acc, 0, 0, 0);
            }
            #pragma unroll
            for (int r = 0; r < 4; ++r) {
                float v = acc[r] * invb[quad * 4 + r];
                unsigned short h, l; split2(v, &h, &l);
                Wh[(quad * 4 + r) * WS + 16 * w + row] = h;
                Wl[(quad * 4 + r) * WS + 16 * w + row] = l;
            }
        } else if (s == 0) {
            float iv0 = invb[0];                 // finalize A row 0
            for (int m = lane; m < 97; m += 64) a0c[m] *= iv0;
        }
        __syncthreads();

        // step 5: h1 strip = relu(AX @ w1); p += a0-weighted rows
        {
            f32x4 acc = {0.f, 0.f, 0.f, 0.f};
            #pragma unroll
            for (int ch = 0; ch < 2; ++ch) {
                int kb = 16 * ch;
                bf16x8 ah = ldf(&Wh[row * WS + kb + quad * 8]);
                bf16x8 al = ldf(&Wl[row * WS + kb + quad * 8]);
                if (ch == 1 && quad < 2) { ah = ZF; al = ZF; }
                bf16x8 bh = ldf(w1T_h + (16 * w + row) * 48 + kb + quad * 8);
                bf16x8 bl = ldf(w1T_l + (16 * w + row) * 48 + kb + quad * 8);
                acc = __builtin_amdgcn_mfma_f32_16x16x32_bf16(ah, bh, acc, 0, 0, 0);
                acc = __builtin_amdgcn_mfma_f32_16x16x32_bf16(ah, bl, acc, 0, 0, 0);
                acc = __builtin_amdgcn_mfma_f32_16x16x32_bf16(al, bh, acc, 0, 0, 0);
            }
            float part = 0.f;
            #pragma unroll
            for (int r = 0; r < 4; ++r)
                part += fmaxf(acc[r], 0.f) * a0c[n0g + quad * 4 + r];
            part += __shfl_xor(part, 16);
            part += __shfl_xor(part, 32);
            if (quad == 0) pacc[16 * w + row] += part;
        }
        __syncthreads();
    }

    // ---------- head ----------
    if (tid < 64) {
        float a = 0.f;
        #pragma unroll 8
        for (int l = 0; l < 64; ++l) a = fmaf(pacc[l], w2[l * 64 + tid], a);
        featb[tid] = fmaxf(a, 0.f);
    }
    __syncthreads();
    if (tid < 64) {
        float a = v_b1[tid];
        #pragma unroll 8
        for (int c = 0; c < 64; ++c) a = fmaf(featb[c], v_w1[c * 64 + tid], a);
        float qd = fmaxf(a, 0.f) * v_w2[tid];
        #pragma unroll
        for (int d = 32; d >= 1; d >>= 1) qd += __shfl_xor(qd, d);
        if (tid == 0) out[b] = qd + v_b2[0];
    }
}

extern "C" void kernel_launch(void* const* d_in, const int* in_sizes, int n_in,
                              void* d_out, int out_size, void* d_ws, size_t ws_size,
                              hipStream_t stream) {
    (void)n_in; (void)ws_size; (void)out_size;
    const float* state = (const float*)d_in[0];
    const float* t_w1  = (const float*)d_in[1];
    const float* t_b1  = (const float*)d_in[2];
    const float* t_w2  = (const float*)d_in[3];
    const float* t_b2  = (const float*)d_in[4];
    const float* w_a   = (const float*)d_in[5];
    const float* w1    = (const float*)d_in[6];
    const float* w2    = (const float*)d_in[7];
    const float* v_w1  = (const float*)d_in[8];
    const float* v_b1  = (const float*)d_in[9];
    const float* v_w2  = (const float*)d_in[10];
    const float* v_b2  = (const float*)d_in[11];
    unsigned short* ws = (unsigned short*)d_ws;
    const int nb = in_sizes[0] / (96 * 64);   // 8192

    vnet_prep<<<1, 256, 0, stream>>>(w_a, w1, ws);
    vnet_kernel<<<nb, 256, 0, stream>>>(state, t_w1, t_b1, t_w2, t_b2, w2,
                                        v_w1, v_b1, v_w2, v_b2, ws, (float*)d_out);
}

// Round 4
// 544.806 us; speedup vs baseline: 1.7150x; 1.2206x over previous
//
#include <hip/hip_runtime.h>

// ValueNetwork B=8192, rows=97 (1 self + 96 human), HUMAN_DIM=48.
// One block (256 thr) per batch. GEMMs on MFMA 16x16x32 bf16 hi/lo split.
// R4: software-pipelined strip loop {softmax(s)+step1(s+1)} B {step4(s)} B
// {step5(s)+step2(s+1)} B with double-buffered W (3 barriers/strip, was 5);
// XT built during staging (no LDS transpose pass); S/AX col 96 via exact fp32
// dot + rank-1 (step2 t<6 only, step4 3 chunks, no ZF masks, no E pads);
// LDS 53,248 B -> 3 blocks/CU; strides 104/56/48 keep <=2-way aliasing on
// XT/E/W (X stays 48: 4-way on X b128 reads, accepted).

#define XS 48     // X plane row stride (ushort)
#define TS 104    // XT plane row stride (ushort)
#define ES 104    // E plane row stride (ushort)
#define WS 56     // W (Xw/AX) plane row stride (ushort)

typedef short bf16x8 __attribute__((ext_vector_type(8)));
typedef float f32x4 __attribute__((ext_vector_type(4)));

__device__ __forceinline__ unsigned rtne_hi(float f) {
    unsigned u = __float_as_uint(f);
    return (u + 0x7fffu + ((u >> 16) & 1u)) & 0xffff0000u;
}
__device__ __forceinline__ void split2(float f, unsigned short* h, unsigned short* l) {
    unsigned hb = rtne_hi(f);
    float r = f - __uint_as_float(hb);
    *h = (unsigned short)(hb >> 16);
    *l = (unsigned short)(__float_as_uint(r) >> 16);
}
__device__ __forceinline__ float bf2f(unsigned short u) {
    return __uint_as_float(((unsigned)u) << 16);
}
__device__ __forceinline__ bf16x8 ldf(const unsigned short* p) {
    return *(const bf16x8*)p;
}

__global__ void vnet_prep(const float* __restrict__ w_a, const float* __restrict__ w1,
                          unsigned short* __restrict__ ws) {
    unsigned short* waT_h = ws;                 // waT[c][k] = w_a[k][c], 48x48
    unsigned short* waT_l = ws + 2304;
    unsigned short* w1T_h = ws + 4608;          // w1T[l][j] = w1[j][l], 64x48
    unsigned short* w1T_l = ws + 4608 + 3072;
    for (int i = threadIdx.x; i < 48 * 48; i += blockDim.x) {
        int c = i / 48, k = i % 48;
        unsigned short h, l; split2(w_a[k * 48 + c], &h, &l);
        waT_h[i] = h; waT_l[i] = l;
    }
    for (int i = threadIdx.x; i < 64 * 48; i += blockDim.x) {
        int lo = i / 48, j = i % 48;
        unsigned short h, l; split2(w1[j * 64 + lo], &h, &l);
        w1T_h[i] = h; w1T_l[i] = l;
    }
}

__global__ __launch_bounds__(256, 3)
void vnet_kernel(const float* __restrict__ state,
                 const float* __restrict__ t_w1, const float* __restrict__ t_b1,
                 const float* __restrict__ t_w2, const float* __restrict__ t_b2,
                 const float* __restrict__ w2,   const float* __restrict__ v_w1,
                 const float* __restrict__ v_b1, const float* __restrict__ v_w2,
                 const float* __restrict__ v_b2, const unsigned short* __restrict__ ws,
                 float* __restrict__ out)
{
    __shared__ __align__(16) unsigned short Xh[97 * XS], Xl[97 * XS];     // 9312 B each
    __shared__ __align__(16) unsigned short XTh[48 * TS], XTl[48 * TS];   // 9984 B each
    __shared__ __align__(16) unsigned short Eh[16 * ES], El[16 * ES];     // 3328 B each
    __shared__ __align__(16) unsigned short W0h[16 * WS], W0l[16 * WS];   // 1792 B each
    __shared__ __align__(16) unsigned short W1h[16 * WS], W1l[16 * WS];   // 1792 B each
    __shared__ float a0c[112];    // A row 0 numerators->probs; [97..111]=0; head reuses [0..63]
    __shared__ float invb[16];    // per-strip-row 1/sum
    __shared__ float e96[16];     // per-strip-row exp(S[n][96]) (unnormalized)
    __shared__ float pacc[64];    // p accumulator; [0..15] self-state temp at setup

    const unsigned short* waT_h = ws;
    const unsigned short* waT_l = ws + 2304;
    const unsigned short* w1T_h = ws + 4608;
    const unsigned short* w1T_l = ws + 4608 + 3072;

    const int tid  = threadIdx.x;
    const int w    = tid >> 6;
    const int lane = tid & 63;
    const int row  = lane & 15;
    const int quad = lane >> 4;
    const int b    = blockIdx.x;
    const float* sb = state + (size_t)b * (96 * 64);
    const bf16x8 ZF = {0, 0, 0, 0, 0, 0, 0, 0};

    // ---------- stage X rows 1..96 AND XT (single split, no transpose pass) ----------
    if (tid < 16) pacc[tid] = sb[tid];           // self-state temp
    for (int i = tid; i < 96 * 12; i += 256) {
        int r = i / 12, q = i % 12;
        float4 v = *(const float4*)(sb + r * 64 + 16 + 4 * q);
        unsigned short h0, l0, h1v, l1, h2, l2, h3, l3;
        split2(v.x, &h0, &l0); split2(v.y, &h1v, &l1);
        split2(v.z, &h2, &l2); split2(v.w, &h3, &l3);
        int m = 1 + r, c0 = 4 * q, o = m * XS + c0;
        *(uint2*)&Xh[o] = make_uint2((unsigned)h0 | ((unsigned)h1v << 16),
                                     (unsigned)h2 | ((unsigned)h3 << 16));
        *(uint2*)&Xl[o] = make_uint2((unsigned)l0 | ((unsigned)l1 << 16),
                                     (unsigned)l2 | ((unsigned)l3 << 16));
        XTh[(c0 + 0) * TS + m] = h0;  XTl[(c0 + 0) * TS + m] = l0;
        XTh[(c0 + 1) * TS + m] = h1v; XTl[(c0 + 1) * TS + m] = l1;
        XTh[(c0 + 2) * TS + m] = h2;  XTl[(c0 + 2) * TS + m] = l2;
        XTh[(c0 + 3) * TS + m] = h3;  XTl[(c0 + 3) * TS + m] = l3;
    }
    __syncthreads();

    // ---------- self MLP ----------
    if (tid < 50) {
        float a = t_b1[tid];
        #pragma unroll
        for (int i = 0; i < 16; ++i) a = fmaf(pacc[i], t_w1[i * 50 + tid], a);
        a0c[tid] = fmaxf(a, 0.f);                // hidden temp
    }
    __syncthreads();
    if (tid < 48) {                              // new_self -> X row0 + XT col0
        float a = t_b2[tid];
        for (int i = 0; i < 50; ++i) a = fmaf(a0c[i], t_w2[i * 48 + tid], a);
        unsigned short h, l; split2(fmaxf(a, 0.f), &h, &l);
        Xh[tid] = h; Xl[tid] = l;
        XTh[tid * TS] = h; XTl[tid * TS] = l;
    }
    if (tid >= 64 && tid < 128) pacc[tid - 64] = 0.f;     // p accumulator
    if (tid >= 128 && tid < 143) a0c[tid - 31] = 0.f;     // a0c[97..111] = 0
    __syncthreads();

    // ---------- prologue: step1(0) -> W0, step2(0) -> E ----------
    // step1: Xw[n][c] = X[strip rows] @ w_a
    {
        if (w < 3) {
            f32x4 acc = {0.f, 0.f, 0.f, 0.f};
            #pragma unroll
            for (int ch = 0; ch < 2; ++ch) {
                int kb = 16 * ch;
                bf16x8 ah = ldf(&Xh[row * XS + kb + quad * 8]);
                bf16x8 al = ldf(&Xl[row * XS + kb + quad * 8]);
                if (ch == 1 && quad < 2) { ah = ZF; al = ZF; }
                bf16x8 bh = ldf(waT_h + (16 * w + row) * 48 + kb + quad * 8);
                bf16x8 bl = ldf(waT_l + (16 * w + row) * 48 + kb + quad * 8);
                acc = __builtin_amdgcn_mfma_f32_16x16x32_bf16(ah, bh, acc, 0, 0, 0);
                acc = __builtin_amdgcn_mfma_f32_16x16x32_bf16(ah, bl, acc, 0, 0, 0);
                acc = __builtin_amdgcn_mfma_f32_16x16x32_bf16(al, bh, acc, 0, 0, 0);
            }
            #pragma unroll
            for (int r = 0; r < 4; ++r) {
                unsigned short h, l; split2(acc[r], &h, &l);
                W0h[(quad * 4 + r) * WS + 16 * w + row] = h;
                W0l[(quad * 4 + r) * WS + 16 * w + row] = l;
            }
        }
    }
    __syncthreads();
    // step2(0): S[n][m] = Xw @ X^T for m in 0..95
    {
        bf16x8 a0h = ldf(&W0h[row * WS + quad * 8]);
        bf16x8 a0l = ldf(&W0l[row * WS + quad * 8]);
        bf16x8 a1h = ldf(&W0h[row * WS + 16 + quad * 8]);
        bf16x8 a1l = ldf(&W0l[row * WS + 16 + quad * 8]);
        if (quad < 2) { a1h = ZF; a1l = ZF; }
        for (int t = w; t < 6; t += 4) {
            int m = 16 * t + row;
            f32x4 acc = {0.f, 0.f, 0.f, 0.f};
            bf16x8 bh = ldf(&Xh[m * XS + quad * 8]);
            bf16x8 bl = ldf(&Xl[m * XS + quad * 8]);
            acc = __builtin_amdgcn_mfma_f32_16x16x32_bf16(a0h, bh, acc, 0, 0, 0);
            acc = __builtin_amdgcn_mfma_f32_16x16x32_bf16(a0h, bl, acc, 0, 0, 0);
            acc = __builtin_amdgcn_mfma_f32_16x16x32_bf16(a0l, bh, acc, 0, 0, 0);
            bh = ldf(&Xh[m * XS + 16 + quad * 8]);
            bl = ldf(&Xl[m * XS + 16 + quad * 8]);
            acc = __builtin_amdgcn_mfma_f32_16x16x32_bf16(a1h, bh, acc, 0, 0, 0);
            acc = __builtin_amdgcn_mfma_f32_16x16x32_bf16(a1h, bl, acc, 0, 0, 0);
            acc = __builtin_amdgcn_mfma_f32_16x16x32_bf16(a1l, bh, acc, 0, 0, 0);
            #pragma unroll
            for (int r = 0; r < 4; ++r) {
                unsigned short h, l; split2(acc[r], &h, &l);
                Eh[(quad * 4 + r) * ES + m] = h;
                El[(quad * 4 + r) * ES + m] = l;
            }
        }
    }
    __syncthreads();

    // ---------- pipelined strip loop ----------
    for (int s = 0; s < 7; ++s) {
        unsigned short* Wsh = (s & 1) ? W1h : W0h;   // this strip's buffer
        unsigned short* Wsl = (s & 1) ? W1l : W0l;
        unsigned short* Wnh = (s & 1) ? W0h : W1h;   // next strip's buffer
        unsigned short* Wnl = (s & 1) ? W0l : W1l;

        // ---- phase A: step1(s+1) + softmax(s) (incl exact col-96 dot) ----
        if (s < 6 && w < 3) {
            f32x4 acc = {0.f, 0.f, 0.f, 0.f};
            int n = (s + 1) * 16 + row; int nc = n < 97 ? n : 96;  // strip-6 tail
            #pragma unroll
            for (int ch = 0; ch < 2; ++ch) {
                int kb = 16 * ch;
                bf16x8 ah = ldf(&Xh[nc * XS + kb + quad * 8]);
                bf16x8 al = ldf(&Xl[nc * XS + kb + quad * 8]);
                if (ch == 1 && quad < 2) { ah = ZF; al = ZF; }
                bf16x8 bh = ldf(waT_h + (16 * w + row) * 48 + kb + quad * 8);
                bf16x8 bl = ldf(waT_l + (16 * w + row) * 48 + kb + quad * 8);
                acc = __builtin_amdgcn_mfma_f32_16x16x32_bf16(ah, bh, acc, 0, 0, 0);
                acc = __builtin_amdgcn_mfma_f32_16x16x32_bf16(ah, bl, acc, 0, 0, 0);
                acc = __builtin_amdgcn_mfma_f32_16x16x32_bf16(al, bh, acc, 0, 0, 0);
            }
            #pragma unroll
            for (int r = 0; r < 4; ++r) {
                unsigned short h, l; split2(acc[r], &h, &l);
                Wnh[(quad * 4 + r) * WS + 16 * w + row] = h;
                Wnl[(quad * 4 + r) * WS + 16 * w + row] = l;
            }
        }
        {   // softmax over 16 rows, 16 lanes each
            int rw = tid >> 4, mg = tid & 15;
            float s96 = 0.f;
            #pragma unroll
            for (int kk = 0; kk < 3; ++kk) {          // S[rw][96] exact fp32 dot
                int c = mg + 16 * kk;
                float xw = bf2f(Wsh[rw * WS + c]) + bf2f(Wsl[rw * WS + c]);
                float xv = bf2f(Xh[96 * XS + c]) + bf2f(Xl[96 * XS + c]);
                s96 = fmaf(xw, xv, s96);
            }
            s96 += __shfl_xor(s96, 1); s96 += __shfl_xor(s96, 2);
            s96 += __shfl_xor(s96, 4); s96 += __shfl_xor(s96, 8);
            float e0 = __expf(s96);
            float sum = (mg == 0) ? e0 : 0.f;
            if (mg == 0) {
                e96[rw] = e0;
                if (s == 0 && rw == 0) a0c[96] = e0;
            }
            for (int m = mg; m < 96; m += 16) {
                int o = rw * ES + m;
                float f = bf2f(Eh[o]) + bf2f(El[o]);
                float e = __expf(f);                  // |S| bounded; no max-sub
                sum += e;
                unsigned short h, l; split2(e, &h, &l);
                Eh[o] = h; El[o] = l;
                if (s == 0 && rw == 0) a0c[m] = e;    // numerators; scaled in phase B
            }
            sum += __shfl_xor(sum, 1); sum += __shfl_xor(sum, 2);
            sum += __shfl_xor(sum, 4); sum += __shfl_xor(sum, 8);
            if (mg == 0) invb[rw] = 1.f / sum;
        }
        __syncthreads();

        // ---- phase B: step4(s): AX = invb*(E@X + e96*X[96]) -> Wsh/Wsl ----
        if (w < 3) {
            f32x4 acc = {0.f, 0.f, 0.f, 0.f};
            #pragma unroll
            for (int c3 = 0; c3 < 3; ++c3) {
                int mb = 32 * c3;
                bf16x8 ah = ldf(&Eh[row * ES + mb + quad * 8]);
                bf16x8 al = ldf(&El[row * ES + mb + quad * 8]);
                bf16x8 bh = ldf(&XTh[(16 * w + row) * TS + mb + quad * 8]);
                bf16x8 bl = ldf(&XTl[(16 * w + row) * TS + mb + quad * 8]);
                acc = __builtin_amdgcn_mfma_f32_16x16x32_bf16(ah, bh, acc, 0, 0, 0);
                acc = __builtin_amdgcn_mfma_f32_16x16x32_bf16(ah, bl, acc, 0, 0, 0);
                acc = __builtin_amdgcn_mfma_f32_16x16x32_bf16(al, bh, acc, 0, 0, 0);
            }
            int j = 16 * w + row;
            float xv = bf2f(Xh[96 * XS + j]) + bf2f(Xl[96 * XS + j]);
            #pragma unroll
            for (int r = 0; r < 4; ++r) {
                float v = fmaf(e96[quad * 4 + r], xv, acc[r]) * invb[quad * 4 + r];
                unsigned short h, l; split2(v, &h, &l);
                Wsh[(quad * 4 + r) * WS + j] = h;
                Wsl[(quad * 4 + r) * WS + j] = l;
            }
        } else if (s == 0) {
            float iv0 = invb[0];                      // finalize A row 0
            for (int m = lane; m < 97; m += 64) a0c[m] *= iv0;
        }
        __syncthreads();

        // ---- phase C: step5(s) + step2(s+1) ----
        {   // h1 = relu(AX @ w1); p += a0-weighted rows
            f32x4 acc = {0.f, 0.f, 0.f, 0.f};
            #pragma unroll
            for (int ch = 0; ch < 2; ++ch) {
                int kb = 16 * ch;
                bf16x8 ah = ldf(&Wsh[row * WS + kb + quad * 8]);
                bf16x8 al = ldf(&Wsl[row * WS + kb + quad * 8]);
                if (ch == 1 && quad < 2) { ah = ZF; al = ZF; }
                bf16x8 bh = ldf(w1T_h + (16 * w + row) * 48 + kb + quad * 8);
                bf16x8 bl = ldf(w1T_l + (16 * w + row) * 48 + kb + quad * 8);
                acc = __builtin_amdgcn_mfma_f32_16x16x32_bf16(ah, bh, acc, 0, 0, 0);
                acc = __builtin_amdgcn_mfma_f32_16x16x32_bf16(ah, bl, acc, 0, 0, 0);
                acc = __builtin_amdgcn_mfma_f32_16x16x32_bf16(al, bh, acc, 0, 0, 0);
            }
            float part = 0.f;
            #pragma unroll
            for (int r = 0; r < 4; ++r)
                part += fmaxf(acc[r], 0.f) * a0c[s * 16 + quad * 4 + r];
            part += __shfl_xor(part, 16);
            part += __shfl_xor(part, 32);
            if (quad == 0) pacc[16 * w + row] += part;
        }
        if (s < 6) {   // step2(s+1): S = Xw(next) @ X^T, m in 0..95
            bf16x8 a0h = ldf(&Wnh[row * WS + quad * 8]);
            bf16x8 a0l = ldf(&Wnl[row * WS + quad * 8]);
            bf16x8 a1h = ldf(&Wnh[row * WS + 16 + quad * 8]);
            bf16x8 a1l = ldf(&Wnl[row * WS + 16 + quad * 8]);
            if (quad < 2) { a1h = ZF; a1l = ZF; }
            for (int t = w; t < 6; t += 4) {
                int m = 16 * t + row;
                f32x4 acc = {0.f, 0.f, 0.f, 0.f};
                bf16x8 bh = ldf(&Xh[m * XS + quad * 8]);
                bf16x8 bl = ldf(&Xl[m * XS + quad * 8]);
                acc = __builtin_amdgcn_mfma_f32_16x16x32_bf16(a0h, bh, acc, 0, 0, 0);
                acc = __builtin_amdgcn_mfma_f32_16x16x32_bf16(a0h, bl, acc, 0, 0, 0);
                acc = __builtin_amdgcn_mfma_f32_16x16x32_bf16(a0l, bh, acc, 0, 0, 0);
                bh = ldf(&Xh[m * XS + 16 + quad * 8]);
                bl = ldf(&Xl[m * XS + 16 + quad * 8]);
                acc = __builtin_amdgcn_mfma_f32_16x16x32_bf16(a1h, bh, acc, 0, 0, 0);
                acc = __builtin_amdgcn_mfma_f32_16x16x32_bf16(a1h, bl, acc, 0, 0, 0);
                acc = __builtin_amdgcn_mfma_f32_16x16x32_bf16(a1l, bh, acc, 0, 0, 0);
                #pragma unroll
                for (int r = 0; r < 4; ++r) {
                    unsigned short h, l; split2(acc[r], &h, &l);
                    Eh[(quad * 4 + r) * ES + m] = h;
                    El[(quad * 4 + r) * ES + m] = l;
                }
            }
        }
        __syncthreads();
    }

    // ---------- head (featb overlaid on a0c; a0c dead) ----------
    float* featb = a0c;
    if (tid < 64) {
        float a = 0.f;
        #pragma unroll 8
        for (int l = 0; l < 64; ++l) a = fmaf(pacc[l], w2[l * 64 + tid], a);
        featb[tid] = fmaxf(a, 0.f);
    }
    __syncthreads();
    if (tid < 64) {
        float a = v_b1[tid];
        #pragma unroll 8
        for (int c = 0; c < 64; ++c) a = fmaf(featb[c], v_w1[c * 64 + tid], a);
        float qd = fmaxf(a, 0.f) * v_w2[tid];
        #pragma unroll
        for (int d = 32; d >= 1; d >>= 1) qd += __shfl_xor(qd, d);
        if (tid == 0) out[b] = qd + v_b2[0];
    }
}

extern "C" void kernel_launch(void* const* d_in, const int* in_sizes, int n_in,
                              void* d_out, int out_size, void* d_ws, size_t ws_size,
                              hipStream_t stream) {
    (void)n_in; (void)ws_size; (void)out_size;
    const float* state = (const float*)d_in[0];
    const float* t_w1  = (const float*)d_in[1];
    const float* t_b1  = (const float*)d_in[2];
    const float* t_w2  = (const float*)d_in[3];
    const float* t_b2  = (const float*)d_in[4];
    const float* w_a   = (const float*)d_in[5];
    const float* w1    = (const float*)d_in[6];
    const float* w2    = (const float*)d_in[7];
    const float* v_w1  = (const float*)d_in[8];
    const float* v_b1  = (const float*)d_in[9];
    const float* v_w2  = (const float*)d_in[10];
    const float* v_b2  = (const float*)d_in[11];
    unsigned short* ws = (unsigned short*)d_ws;
    const int nb = in_sizes[0] / (96 * 64);   // 8192

    vnet_prep<<<1, 256, 0, stream>>>(w_a, w1, ws);
    vnet_kernel<<<nb, 256, 0, stream>>>(state, t_w1, t_b1, t_w2, t_b2, w2,
                                        v_w1, v_b1, v_w2, v_b2, ws, (float*)d_out);
}